// Round 8
// baseline (206.625 us; speedup 1.0000x reference)
//
#include <hip/hip_runtime.h>
#include <math.h>

namespace {

constexpr int kB = 4;
constexpr int kL = 4096;
constexpr int kD = 1024;
constexpr int kN = 64;
constexpr int kM = kB * kL;               // 16384 rows (b*L + l)
constexpr size_t kBLN = (size_t)kM * kN;  // 1,048,576 floats per u/y buffer
constexpr int kSplit = 8;                 // K-split for GEMM1
constexpr int kKRange = kD / kSplit;      // 128
constexpr int kBK1 = 32;                  // GEMM1 K-chunk in LDS
constexpr int kBK2 = 16;                  // GEMM2 K-chunk in LDS
constexpr int kChunks = 64;               // scan chunks per sequence
constexpr int kChunkLen = kL / kChunks;   // 64 steps per chunk
constexpr size_t kHloc = (size_t)kB * kChunks * kN;  // 16384 floats

// ---------------------------------------------------------------------------
// GEMM1: u[m][n] (+)= sum_d x[m][d] * W_in[n][d] over this block's K-range.
// grid (kM/64, kSplit=8), block 64 (one wave). 64x64 tile, 8x8 micro, BK=32.
// R6 diagnosis: occupancy 8.9% (4 waves/CU), VALUBusy 30% -> latency-bound.
// kSplit=8 -> 2048 waves = 8 waves/CU; LDS 17.4KB (cap 9 blocks/CU).
// Epilogue: kAtomic=false -> plain stores to partial z (proven R6 pattern);
// kAtomic=true -> atomicAdd into one buffer (fallback if ws is small; risk:
// 8.4M L2 RMWs could be ~27us if slices do 1 atomic/cyc uncoalesced).
// ---------------------------------------------------------------------------
template <bool kAtomic>
__global__ __launch_bounds__(64) void k_gemm_in(const float* __restrict__ x,
                                                const float* __restrict__ Win,
                                                float* __restrict__ u) {
  __shared__ __align__(16) float As[kBK1][68];  // [k][m]
  __shared__ __align__(16) float Bs[kBK1][68];  // [k][n]
  const int t = threadIdx.x;
  const int m_blk = blockIdx.x * 64;
  const int z = blockIdx.y;

  const int tm = t & 7;
  const int tn = t >> 3;
  const int m0 = tm * 8;
  const int n0 = tn * 8;

  const int kk = t & 31;    // lane's k within chunk
  const int half = t >> 5;  // 0/1: which 32-row half this lane stages

  float acc[8][8];
#pragma unroll
  for (int i = 0; i < 8; ++i)
#pragma unroll
    for (int j = 0; j < 8; ++j) acc[i][j] = 0.0f;

  for (int kc = 0; kc < kKRange; kc += kBK1) {
    const int k0 = z * kKRange + kc;
    // Transpose-on-load: lane owns column k0+kk; gathers 4 consecutive rows
    // per float4 -> min-cycle ds_write_b128 (exactly 8 words/bank/instr).
#pragma unroll
    for (int i = 0; i < 8; ++i) {
      const int m4 = half * 32 + i * 4;
      const float* src = &x[(size_t)(m_blk + m4) * kD + k0 + kk];
      float4 v = make_float4(src[0], src[kD], src[2 * kD], src[3 * kD]);
      *reinterpret_cast<float4*>(&As[kk][m4]) = v;
    }
#pragma unroll
    for (int i = 0; i < 8; ++i) {
      const int n4 = half * 32 + i * 4;
      const float* src = &Win[(size_t)n4 * kD + k0 + kk];
      float4 v = make_float4(src[0], src[kD], src[2 * kD], src[3 * kD]);
      *reinterpret_cast<float4*>(&Bs[kk][n4]) = v;
    }
    __syncthreads();

#pragma unroll 4
    for (int k = 0; k < kBK1; ++k) {
      float4 a0 = *reinterpret_cast<const float4*>(&As[k][m0]);
      float4 a1 = *reinterpret_cast<const float4*>(&As[k][m0 + 4]);
      float4 b0 = *reinterpret_cast<const float4*>(&Bs[k][n0]);
      float4 b1 = *reinterpret_cast<const float4*>(&Bs[k][n0 + 4]);
      float a[8] = {a0.x, a0.y, a0.z, a0.w, a1.x, a1.y, a1.z, a1.w};
      float b[8] = {b0.x, b0.y, b0.z, b0.w, b1.x, b1.y, b1.z, b1.w};
#pragma unroll
      for (int i = 0; i < 8; ++i)
#pragma unroll
        for (int j = 0; j < 8; ++j) acc[i][j] = fmaf(a[i], b[j], acc[i][j]);
    }
    __syncthreads();
  }

  if constexpr (kAtomic) {
#pragma unroll
    for (int i = 0; i < 8; ++i) {
      float* dst = &u[(size_t)(m_blk + m0 + i) * kN + n0];
#pragma unroll
      for (int j = 0; j < 8; ++j) atomicAdd(dst + j, acc[i][j]);
    }
  } else {
    float* up = u + (size_t)z * kBLN;
#pragma unroll
    for (int i = 0; i < 8; ++i) {
      const size_t o = (size_t)(m_blk + m0 + i) * kN + n0;
      *reinterpret_cast<float4*>(&up[o]) =
          make_float4(acc[i][0], acc[i][1], acc[i][2], acc[i][3]);
      *reinterpret_cast<float4*>(&up[o + 4]) =
          make_float4(acc[i][4], acc[i][5], acc[i][6], acc[i][7]);
    }
  }
}

// ---------------------------------------------------------------------------
// ZOH discretization helper (per lane n)
// ---------------------------------------------------------------------------
__device__ __forceinline__ void zoh(const float* __restrict__ logA,
                                    const float* __restrict__ logdt, int n,
                                    float& A, float& dt, float& Abar) {
  dt = expf(logdt[0]);
  A = -expf(logA[n]);
  Abar = expf(A * dt);
}

__device__ __forceinline__ float zoh_bbar(float A, float dt, float Abar,
                                          float Bp) {
  const bool small = fabsf(A) < 1e-6f;
  const float denom = small ? 1.0f : A;
  float frac = (Abar - 1.0f) / denom;
  frac = small ? dt : frac;
  return frac * Bp;
}

// ---------------------------------------------------------------------------
// Scan phase 1: sum kParts u-partials (stride kBLN), pre-scale by Bbar
// (stored back into partial 0), chunk-local final state -> hloc.
// grid (kChunks, kB), block 64 (lane = n).
// ---------------------------------------------------------------------------
template <int kParts>
__global__ __launch_bounds__(64) void k_scan_local(
    const float* __restrict__ logA, const float* __restrict__ Bparam,
    const float* __restrict__ logdt, float* __restrict__ u,
    float* __restrict__ hloc) {
  const int n = threadIdx.x;
  const int c = blockIdx.x;
  const int b = blockIdx.y;
  float A, dt, Abar;
  zoh(logA, logdt, n, A, dt, Abar);
  const float Bbar = zoh_bbar(A, dt, Abar, Bparam[n]);

  const size_t base = ((size_t)b * kL + (size_t)c * kChunkLen) * kN + n;

  float h = 0.0f;
#pragma unroll 8
  for (int s = 0; s < kChunkLen; ++s) {
    const size_t idx = base + (size_t)s * kN;
    float uu = 0.0f;
#pragma unroll
    for (int p = 0; p < kParts; ++p) uu += u[idx + (size_t)p * kBLN];
    const float ub = uu * Bbar;
    h = fmaf(h, Abar, ub);
    u[idx] = ub;  // partial 0 <- Bbar-scaled summed u (for the replay pass)
  }
  hloc[((size_t)b * kChunks + c) * kN + n] = h;
}

// ---------------------------------------------------------------------------
// Scan phase 2 (fused combine+apply): recompute own chunk-init state via
// Horner prefix over hloc[0..c-1] (L2-resident, prefetch distance 2), then
// replay the chunk writing y = h*C. grid (kChunks, kB), block 64.
// ---------------------------------------------------------------------------
__global__ __launch_bounds__(64) void k_scan_apply(
    const float* __restrict__ logA, const float* __restrict__ Cparam,
    const float* __restrict__ logdt, const float* __restrict__ u,
    float* __restrict__ ybuf, const float* __restrict__ hloc) {
  const int n = threadIdx.x;
  const int c = blockIdx.x;
  const int b = blockIdx.y;
  float A, dt, Abar;
  zoh(logA, logdt, n, A, dt, Abar);
  const float C = Cparam[n];
  const float AbarC = expf(A * dt * (float)kChunkLen);  // Abar^kChunkLen

  const size_t hbase = (size_t)b * kChunks * kN + n;

  // Horner prefix: h_init = sum_{j<c} hloc[j] * AbarC^(c-1-j)
  float h = 0.0f;
  if (c > 0) {
    float p0 = hloc[hbase];  // j=0
    float p1 = (c > 1) ? hloc[hbase + kN] : 0.0f;
    for (int j = 0; j < c; ++j) {
      const float cur = p0;
      p0 = p1;
      p1 = (j + 2 < c) ? hloc[hbase + (size_t)(j + 2) * kN] : 0.0f;
      h = fmaf(h, AbarC, cur);
    }
  }

  const size_t base = ((size_t)b * kL + (size_t)c * kChunkLen) * kN + n;
#pragma unroll 8
  for (int s = 0; s < kChunkLen; ++s) {
    const size_t idx = base + (size_t)s * kN;
    h = fmaf(h, Abar, u[idx]);  // u holds Bbar-scaled input
    ybuf[idx] = h * C;
  }
}

// ---------------------------------------------------------------------------
// GEMM2: out[m][d] = sum_n y[m][n] * W_out[d][n]
// grid (kM/64, kD/128), block 128 (2 waves). Tile 64x128, 8x8 micro, BK=16.
// R6 fix: LDS 51.6KB capped occupancy at 6 waves/CU; BK=16 -> 12.8KB ->
// 12 waves/CU (VGPR-capped), grid supplies 16.
// ---------------------------------------------------------------------------
__global__ __launch_bounds__(128) void k_gemm_out(
    const float* __restrict__ y, const float* __restrict__ Wout,
    float* __restrict__ out) {
  __shared__ __align__(16) float Ys[kBK2][68];   // [k][m]
  __shared__ __align__(16) float Ws[kBK2][132];  // [k][d]
  const int t = threadIdx.x;
  const int m_blk = blockIdx.x * 64;
  const int d_blk = blockIdx.y * 128;

  const int kk = t & 15;  // lane's k within chunk
  const int g = t >> 4;   // 8 staging groups

  const int tm = t & 7;
  const int tn = t >> 3;  // 0..15
  const int m0 = tm * 8;
  const int n0 = tn * 8;

  float acc[8][8];
#pragma unroll
  for (int i = 0; i < 8; ++i)
#pragma unroll
    for (int j = 0; j < 8; ++j) acc[i][j] = 0.0f;

  for (int kc = 0; kc < kN; kc += kBK2) {
    // y tile: 64 rows x 16 k. 8 groups x 2 float4-rows each.
#pragma unroll
    for (int i = 0; i < 2; ++i) {
      const int m4 = g * 8 + i * 4;
      const float* src = &y[(size_t)(m_blk + m4) * kN + kc + kk];
      *reinterpret_cast<float4*>(&Ys[kk][m4]) =
          make_float4(src[0], src[kN], src[2 * kN], src[3 * kN]);
    }
    // W_out tile: 128 rows x 16 k. 8 groups x 4 float4-rows each.
#pragma unroll
    for (int i = 0; i < 4; ++i) {
      const int d4 = g * 16 + i * 4;
      const float* src = &Wout[(size_t)(d_blk + d4) * kN + kc + kk];
      *reinterpret_cast<float4*>(&Ws[kk][d4]) =
          make_float4(src[0], src[kN], src[2 * kN], src[3 * kN]);
    }
    __syncthreads();

#pragma unroll 4
    for (int k = 0; k < kBK2; ++k) {
      float4 a0 = *reinterpret_cast<const float4*>(&Ys[k][m0]);
      float4 a1 = *reinterpret_cast<const float4*>(&Ys[k][m0 + 4]);
      float4 b0 = *reinterpret_cast<const float4*>(&Ws[k][n0]);
      float4 b1 = *reinterpret_cast<const float4*>(&Ws[k][n0 + 4]);
      float a[8] = {a0.x, a0.y, a0.z, a0.w, a1.x, a1.y, a1.z, a1.w};
      float b[8] = {b0.x, b0.y, b0.z, b0.w, b1.x, b1.y, b1.z, b1.w};
#pragma unroll
      for (int i = 0; i < 8; ++i)
#pragma unroll
        for (int j = 0; j < 8; ++j) acc[i][j] = fmaf(a[i], b[j], acc[i][j]);
    }
    __syncthreads();
  }

#pragma unroll
  for (int i = 0; i < 8; ++i) {
    const size_t o = (size_t)(m_blk + m0 + i) * kD + d_blk + n0;
    *reinterpret_cast<float4*>(&out[o]) =
        make_float4(acc[i][0], acc[i][1], acc[i][2], acc[i][3]);
    *reinterpret_cast<float4*>(&out[o + 4]) =
        make_float4(acc[i][4], acc[i][5], acc[i][6], acc[i][7]);
  }
}

}  // namespace

// ---------------------------------------------------------------------------
// Two ws layouts, chosen at host level by ws_size (constant per session, so
// every call does identical work — graph-safe):
//  PARTIALS (needs 32MB+64KB): [0,8*kBLN) split-K partials; scan_local<8>
//    sums them into partial 0 (Bbar-scaled); y overwrites partial 1;
//    hloc at 8*kBLN. No atomics anywhere.
//  ATOMIC (8MB+64KB): [0,kBLN) u (zeroed, atomicAdd); y at kBLN;
//    hloc at 2*kBLN.
// ---------------------------------------------------------------------------
extern "C" void kernel_launch(void* const* d_in, const int* in_sizes, int n_in,
                              void* d_out, int out_size, void* d_ws,
                              size_t ws_size, hipStream_t stream) {
  const float* x = (const float*)d_in[0];
  const float* Win = (const float*)d_in[1];
  const float* Wout = (const float*)d_in[2];
  const float* logA = (const float*)d_in[3];
  const float* Bparam = (const float*)d_in[4];
  const float* Cparam = (const float*)d_in[5];
  const float* logdt = (const float*)d_in[6];
  float* out = (float*)d_out;
  float* ws = (float*)d_ws;

  const bool partials = ws_size >= (8 * kBLN + kHloc) * sizeof(float);

  if (partials) {
    float* hloc = ws + 8 * kBLN;
    k_gemm_in<false><<<dim3(kM / 64, kSplit), 64, 0, stream>>>(x, Win, ws);
    k_scan_local<kSplit><<<dim3(kChunks, kB), 64, 0, stream>>>(
        logA, Bparam, logdt, ws, hloc);
    k_scan_apply<<<dim3(kChunks, kB), 64, 0, stream>>>(
        logA, Cparam, logdt, ws, ws + kBLN, hloc);
    k_gemm_out<<<dim3(kM / 64, kD / 128), 128, 0, stream>>>(ws + kBLN, Wout,
                                                            out);
  } else {
    float* hloc = ws + 2 * kBLN;
    hipMemsetAsync(ws, 0, kBLN * sizeof(float), stream);  // zero u
    k_gemm_in<true><<<dim3(kM / 64, kSplit), 64, 0, stream>>>(x, Win, ws);
    k_scan_local<1><<<dim3(kChunks, kB), 64, 0, stream>>>(logA, Bparam, logdt,
                                                          ws, hloc);
    k_scan_apply<<<dim3(kChunks, kB), 64, 0, stream>>>(
        logA, Cparam, logdt, ws, ws + kBLN, hloc);
    k_gemm_out<<<dim3(kM / 64, kD / 128), 128, 0, stream>>>(ws + kBLN, Wout,
                                                            out);
  }
}

// Round 12
// 202.274 us; speedup vs baseline: 1.0215x; 1.0215x over previous
//
#include <hip/hip_runtime.h>
#include <math.h>

namespace {

constexpr int kB = 4;
constexpr int kL = 4096;
constexpr int kD = 1024;
constexpr int kN = 64;
constexpr int kM = kB * kL;               // 16384 rows (b*L + l)
constexpr size_t kBLN = (size_t)kM * kN;  // 1,048,576 floats per u/y buffer
constexpr int kSplit = 8;                 // K-split for GEMM1
constexpr int kKRange = kD / kSplit;      // 128
constexpr int kBK1 = 32;                  // GEMM1 K-chunk in LDS
constexpr int kBK2 = 16;                  // GEMM2 K-chunk in LDS
constexpr int kChunks = 64;               // scan chunks per sequence
constexpr int kChunkLen = kL / kChunks;   // 64 steps per chunk
constexpr size_t kHloc = (size_t)kB * kChunks * kN;  // 16384 floats

// ---------------------------------------------------------------------------
// GEMM1: u_partial[z][m][n] = sum over z's K-range of x[m][d]*W_in[n][d].
// grid (kM/64, 8), block 64. 64x64 tile, 8x8 micro, BK=32.
// R8 lesson: VGPR=68 proved the compiler serialized staging (load4->wait->
// ds_write x16, ~12.8k cyc/chunk exposed; VALUBusy 24%). Fix: explicit
// float4 reg arrays force bulk issue + one drain, and next chunk's loads are
// issued BEFORE this chunk's FMA loop so latency hides under 4096 cyc of
// compute. __launch_bounds__(64,2) lets VGPR grow to ~150 (cap 256).
// ---------------------------------------------------------------------------
__global__ __launch_bounds__(64, 2) void k_gemm_in(
    const float* __restrict__ x, const float* __restrict__ Win,
    float* __restrict__ u) {
  __shared__ __align__(16) float As[kBK1][68];  // [k][m]
  __shared__ __align__(16) float Bs[kBK1][68];  // [k][n]
  const int t = threadIdx.x;
  const int m_blk = blockIdx.x * 64;
  const int z = blockIdx.y;

  const int tm = t & 7;
  const int tn = t >> 3;
  const int m0 = tm * 8;
  const int n0 = tn * 8;

  const int kk = t & 31;    // lane's k within chunk
  const int half = t >> 5;  // 0/1: which 32-row half this lane stages

  float4 ra[8], rb[8];  // staged tiles — statically indexed => stay in VGPRs
  auto load_chunk = [&](int kc) {
    const int k0 = z * kKRange + kc;
#pragma unroll
    for (int i = 0; i < 8; ++i) {
      const int r4 = half * 32 + i * 4;
      const float* sa = &x[(size_t)(m_blk + r4) * kD + k0 + kk];
      ra[i] = make_float4(sa[0], sa[kD], sa[2 * kD], sa[3 * kD]);
      const float* sb = &Win[(size_t)r4 * kD + k0 + kk];
      rb[i] = make_float4(sb[0], sb[kD], sb[2 * kD], sb[3 * kD]);
    }
  };

  float acc[8][8];
#pragma unroll
  for (int i = 0; i < 8; ++i)
#pragma unroll
    for (int j = 0; j < 8; ++j) acc[i][j] = 0.0f;

  load_chunk(0);
  for (int kc = 0; kc < kKRange; kc += kBK1) {
    // Commit staged regs to LDS (transpose layout [k][m]); conflict-free
    // ds_write_b128. Prev iteration's FMA consumers are behind the barrier.
#pragma unroll
    for (int i = 0; i < 8; ++i) {
      const int r4 = half * 32 + i * 4;
      *reinterpret_cast<float4*>(&As[kk][r4]) = ra[i];
      *reinterpret_cast<float4*>(&Bs[kk][r4]) = rb[i];
    }
    __syncthreads();
    if (kc + kBK1 < kKRange) load_chunk(kc + kBK1);  // hide under FMA below

#pragma unroll 4
    for (int k = 0; k < kBK1; ++k) {
      float4 a0 = *reinterpret_cast<const float4*>(&As[k][m0]);
      float4 a1 = *reinterpret_cast<const float4*>(&As[k][m0 + 4]);
      float4 b0 = *reinterpret_cast<const float4*>(&Bs[k][n0]);
      float4 b1 = *reinterpret_cast<const float4*>(&Bs[k][n0 + 4]);
      float a[8] = {a0.x, a0.y, a0.z, a0.w, a1.x, a1.y, a1.z, a1.w};
      float b[8] = {b0.x, b0.y, b0.z, b0.w, b1.x, b1.y, b1.z, b1.w};
#pragma unroll
      for (int i = 0; i < 8; ++i)
#pragma unroll
        for (int j = 0; j < 8; ++j) acc[i][j] = fmaf(a[i], b[j], acc[i][j]);
    }
    __syncthreads();
  }

  float* up = u + (size_t)z * kBLN;
#pragma unroll
  for (int i = 0; i < 8; ++i) {
    const size_t o = (size_t)(m_blk + m0 + i) * kN + n0;
    *reinterpret_cast<float4*>(&up[o]) =
        make_float4(acc[i][0], acc[i][1], acc[i][2], acc[i][3]);
    *reinterpret_cast<float4*>(&up[o + 4]) =
        make_float4(acc[i][4], acc[i][5], acc[i][6], acc[i][7]);
  }
}

// ---------------------------------------------------------------------------
// ZOH discretization helper (per lane n)
// ---------------------------------------------------------------------------
__device__ __forceinline__ void zoh(const float* __restrict__ logA,
                                    const float* __restrict__ logdt, int n,
                                    float& A, float& dt, float& Abar) {
  dt = expf(logdt[0]);
  A = -expf(logA[n]);
  Abar = expf(A * dt);
}

__device__ __forceinline__ float zoh_bbar(float A, float dt, float Abar,
                                          float Bp) {
  const bool small = fabsf(A) < 1e-6f;
  const float denom = small ? 1.0f : A;
  float frac = (Abar - 1.0f) / denom;
  frac = small ? dt : frac;
  return frac * Bp;
}

// ---------------------------------------------------------------------------
// Reduce: u[idx] (partial 0, in place) = Bbar[n] * sum_p partial_p[idx].
// R8 lesson: this 32MB summation sat on the 256-wave serial scan's critical
// path. Exact cover: 1024 blocks x 256 thr x float4 = kBLN.
// 4096 waves -> BW-bound (~36MB, L3-hot) instead of latency-bound.
// ---------------------------------------------------------------------------
__global__ __launch_bounds__(256) void k_reduce(
    const float* __restrict__ logA, const float* __restrict__ Bparam,
    const float* __restrict__ logdt, float* __restrict__ u) {
  __shared__ float sB[kN];
  const int t = threadIdx.x;
  if (t < kN) {
    float A, dt, Abar;
    zoh(logA, logdt, t, A, dt, Abar);
    sB[t] = zoh_bbar(A, dt, Abar, Bparam[t]);
  }
  __syncthreads();

  const size_t i4 = ((size_t)blockIdx.x * 256 + t) * 4;
  float4 acc = *reinterpret_cast<const float4*>(&u[i4]);
#pragma unroll
  for (int p = 1; p < kSplit; ++p) {
    float4 v = *reinterpret_cast<const float4*>(&u[i4 + (size_t)p * kBLN]);
    acc.x += v.x;
    acc.y += v.y;
    acc.z += v.z;
    acc.w += v.w;
  }
  const int n0 = (int)(i4 & (kN - 1));  // 4-aligned, so n0+3 < 64
  acc.x *= sB[n0];
  acc.y *= sB[n0 + 1];
  acc.z *= sB[n0 + 2];
  acc.w *= sB[n0 + 3];
  *reinterpret_cast<float4*>(&u[i4]) = acc;
}

// ---------------------------------------------------------------------------
// Scan phase 1: chunk-local final state over Bbar-scaled u (now only 4MB,
// L3-hot). grid (kChunks, kB), block 64 (lane = n).
// ---------------------------------------------------------------------------
__global__ __launch_bounds__(64) void k_scan_local(
    const float* __restrict__ logA, const float* __restrict__ logdt,
    const float* __restrict__ u, float* __restrict__ hloc) {
  const int n = threadIdx.x;
  const int c = blockIdx.x;
  const int b = blockIdx.y;
  float A, dt, Abar;
  zoh(logA, logdt, n, A, dt, Abar);

  const size_t base = ((size_t)b * kL + (size_t)c * kChunkLen) * kN + n;
  float h = 0.0f;
#pragma unroll 8
  for (int s = 0; s < kChunkLen; ++s) {
    h = fmaf(h, Abar, u[base + (size_t)s * kN]);
  }
  hloc[((size_t)b * kChunks + c) * kN + n] = h;
}

// ---------------------------------------------------------------------------
// Scan phase 2 (fused combine+apply): Horner prefix over hloc[0..c-1]
// (L2-resident, prefetch distance 2), then replay the chunk writing y=h*C.
// grid (kChunks, kB), block 64.
// ---------------------------------------------------------------------------
__global__ __launch_bounds__(64) void k_scan_apply(
    const float* __restrict__ logA, const float* __restrict__ Cparam,
    const float* __restrict__ logdt, const float* __restrict__ u,
    float* __restrict__ ybuf, const float* __restrict__ hloc) {
  const int n = threadIdx.x;
  const int c = blockIdx.x;
  const int b = blockIdx.y;
  float A, dt, Abar;
  zoh(logA, logdt, n, A, dt, Abar);
  const float C = Cparam[n];
  const float AbarC = expf(A * dt * (float)kChunkLen);  // Abar^kChunkLen

  const size_t hbase = (size_t)b * kChunks * kN + n;
  float h = 0.0f;
  if (c > 0) {
    float p0 = hloc[hbase];
    float p1 = (c > 1) ? hloc[hbase + kN] : 0.0f;
    for (int j = 0; j < c; ++j) {
      const float cur = p0;
      p0 = p1;
      p1 = (j + 2 < c) ? hloc[hbase + (size_t)(j + 2) * kN] : 0.0f;
      h = fmaf(h, AbarC, cur);
    }
  }

  const size_t base = ((size_t)b * kL + (size_t)c * kChunkLen) * kN + n;
#pragma unroll 8
  for (int s = 0; s < kChunkLen; ++s) {
    const size_t idx = base + (size_t)s * kN;
    h = fmaf(h, Abar, u[idx]);  // u holds Bbar-scaled input
    ybuf[idx] = h * C;
  }
}

// ---------------------------------------------------------------------------
// GEMM2: out[m][d] = sum_n y[m][n] * W_out[d][n]
// grid (kM/64, kD/128), block 128 (2 waves). Tile 64x128, 8x8 micro, BK=16.
// Same reg-staged pipeline as GEMM1 (R8's serialization fix).
// ---------------------------------------------------------------------------
__global__ __launch_bounds__(128, 2) void k_gemm_out(
    const float* __restrict__ y, const float* __restrict__ Wout,
    float* __restrict__ out) {
  __shared__ __align__(16) float Ys[kBK2][68];   // [k][m]
  __shared__ __align__(16) float Ws[kBK2][132];  // [k][d]
  const int t = threadIdx.x;
  const int m_blk = blockIdx.x * 64;
  const int d_blk = blockIdx.y * 128;

  const int kk = t & 15;  // lane's k within chunk
  const int g = t >> 4;   // 8 staging groups

  const int tm = t & 7;
  const int tn = t >> 3;  // 0..15
  const int m0 = tm * 8;
  const int n0 = tn * 8;

  float4 ry[2], rw[4];  // staged tiles
  auto load_chunk = [&](int kc) {
#pragma unroll
    for (int i = 0; i < 2; ++i) {
      const int m4 = g * 8 + i * 4;
      const float* s = &y[(size_t)(m_blk + m4) * kN + kc + kk];
      ry[i] = make_float4(s[0], s[kN], s[2 * kN], s[3 * kN]);
    }
#pragma unroll
    for (int i = 0; i < 4; ++i) {
      const int d4 = g * 16 + i * 4;
      const float* s = &Wout[(size_t)(d_blk + d4) * kN + kc + kk];
      rw[i] = make_float4(s[0], s[kN], s[2 * kN], s[3 * kN]);
    }
  };

  float acc[8][8];
#pragma unroll
  for (int i = 0; i < 8; ++i)
#pragma unroll
    for (int j = 0; j < 8; ++j) acc[i][j] = 0.0f;

  load_chunk(0);
  for (int kc = 0; kc < kN; kc += kBK2) {
#pragma unroll
    for (int i = 0; i < 2; ++i)
      *reinterpret_cast<float4*>(&Ys[kk][g * 8 + i * 4]) = ry[i];
#pragma unroll
    for (int i = 0; i < 4; ++i)
      *reinterpret_cast<float4*>(&Ws[kk][g * 16 + i * 4]) = rw[i];
    __syncthreads();
    if (kc + kBK2 < kN) load_chunk(kc + kBK2);

#pragma unroll 4
    for (int k = 0; k < kBK2; ++k) {
      float4 a0 = *reinterpret_cast<const float4*>(&Ys[k][m0]);
      float4 a1 = *reinterpret_cast<const float4*>(&Ys[k][m0 + 4]);
      float4 b0 = *reinterpret_cast<const float4*>(&Ws[k][n0]);
      float4 b1 = *reinterpret_cast<const float4*>(&Ws[k][n0 + 4]);
      float a[8] = {a0.x, a0.y, a0.z, a0.w, a1.x, a1.y, a1.z, a1.w};
      float b[8] = {b0.x, b0.y, b0.z, b0.w, b1.x, b1.y, b1.z, b1.w};
#pragma unroll
      for (int i = 0; i < 8; ++i)
#pragma unroll
        for (int j = 0; j < 8; ++j) acc[i][j] = fmaf(a[i], b[j], acc[i][j]);
    }
    __syncthreads();
  }

#pragma unroll
  for (int i = 0; i < 8; ++i) {
    const size_t o = (size_t)(m_blk + m0 + i) * kD + d_blk + n0;
    *reinterpret_cast<float4*>(&out[o]) =
        make_float4(acc[i][0], acc[i][1], acc[i][2], acc[i][3]);
    *reinterpret_cast<float4*>(&out[o + 4]) =
        make_float4(acc[i][4], acc[i][5], acc[i][6], acc[i][7]);
  }
}

}  // namespace

// ---------------------------------------------------------------------------
// Workspace (floats), proven fit in R8 (ran this branch):
//   [0, 8*kBLN)      : split-K partials. Partial 0 becomes Bbar-scaled
//                      summed u (k_reduce, in place). Partial 1 becomes y.
//   [8*kBLN, +16384) : hloc.
// Total: 32 MiB + 64 KiB. No atomics anywhere.
// ---------------------------------------------------------------------------
extern "C" void kernel_launch(void* const* d_in, const int* in_sizes, int n_in,
                              void* d_out, int out_size, void* d_ws,
                              size_t ws_size, hipStream_t stream) {
  const float* x = (const float*)d_in[0];
  const float* Win = (const float*)d_in[1];
  const float* Wout = (const float*)d_in[2];
  const float* logA = (const float*)d_in[3];
  const float* Bparam = (const float*)d_in[4];
  const float* Cparam = (const float*)d_in[5];
  const float* logdt = (const float*)d_in[6];
  float* out = (float*)d_out;
  float* ws = (float*)d_ws;
  float* hloc = ws + 8 * kBLN;

  k_gemm_in<<<dim3(kM / 64, kSplit), 64, 0, stream>>>(x, Win, ws);
  k_reduce<<<dim3((int)(kBLN / 1024)), 256, 0, stream>>>(logA, Bparam, logdt,
                                                         ws);
  k_scan_local<<<dim3(kChunks, kB), 64, 0, stream>>>(logA, logdt, ws, hloc);
  k_scan_apply<<<dim3(kChunks, kB), 64, 0, stream>>>(logA, Cparam, logdt, ws,
                                                     ws + kBLN, hloc);
  k_gemm_out<<<dim3(kM / 64, kD / 128), 128, 0, stream>>>(ws + kBLN, Wout,
                                                          out);
}